// Round 6
// baseline (91.641 us; speedup 1.0000x reference)
//
#include <hip/hip_runtime.h>

// APoT quantization (BITS=5, K=2 -> N=2 banks, 4 levels/bank), elementwise.
// bank0 = {0, 1, 0.25, 0.0625}, bank1 = {0, 0.5, 0.125, 0.03125}, LMAX = 1.5
//
// Numeric contract (VERIFIED round 4, absmax = 0.0): all-f32 with
// reciprocal-multiply normalization xn = x * (1.0f/(alpha + 1e-8f))
// (XLA div->recip*mul rewrite; 1/6.0f = 0x3E2AAAAB), argmin first-index-wins,
// residual clip, acc/1.5f, *alpha_f32.  ARITHMETIC IS FROZEN.
//
// Memory path (round 6): input == 256 MiB == L3 capacity, so streaming it
// self-thrashes (round-5 profile: FETCH = 134 MB = 50% resident). Partition:
//   [0, 75%)  cacheable loads  -> 192 MiB working set, stays L3-resident
//   [75%, n)  nontemporal loads -> never allocate, always HBM (~67 MB/replay)
// Output stores stay nontemporal (round-5 win: bypass L3, don't evict input).
// Unroll x2 grid-stride for 2 outstanding wave-loads (Little's law margin).

typedef float vfloat4 __attribute__((ext_vector_type(4)));

__device__ __forceinline__ float apot_one(float x, float inv, float alpha_f) {
    float xn = fminf(fmaxf(x * inv, -1.0f), 1.0f);
    float s  = (xn > 0.0f) ? 1.0f : ((xn < 0.0f) ? -1.0f : 0.0f);
    float a  = fabsf(xn);

    // Bank 0: levels {0, 1, 0.25, 0.0625}; argmin first-index-wins (strict <)
    float best = a;          // |a - 0|
    float c0   = 0.0f;
    float d;
    d = fabsf(a - 1.0f);      if (d < best) { best = d; c0 = 1.0f; }
    d = fabsf(a - 0.25f);     if (d < best) { best = d; c0 = 0.25f; }
    d = fabsf(a - 0.0625f);   if (d < best) { best = d; c0 = 0.0625f; }
    float res = fmaxf(a - c0, 0.0f);   // exact in f32

    // Bank 1: levels {0, 0.5, 0.125, 0.03125}
    best = res;               // |res - 0| (res >= 0)
    float c1 = 0.0f;
    d = fabsf(res - 0.5f);     if (d < best) { best = d; c1 = 0.5f; }
    d = fabsf(res - 0.125f);   if (d < best) { best = d; c1 = 0.125f; }
    d = fabsf(res - 0.03125f); if (d < best) { best = d; c1 = 0.03125f; }

    float acc = c0 + c1;                               // exact
    float ah  = fminf(fmaxf(acc / 1.5f, 0.0f), 1.0f);  // (LMAX+EPS) -> 1.5f
    return s * ah * alpha_f;
}

__device__ __forceinline__ vfloat4 apot_vec4(vfloat4 v, float inv, float alpha_f) {
    vfloat4 r;
    r.x = apot_one(v.x, inv, alpha_f);
    r.y = apot_one(v.y, inv, alpha_f);
    r.z = apot_one(v.z, inv, alpha_f);
    r.w = apot_one(v.w, inv, alpha_f);
    return r;
}

__global__ __launch_bounds__(256) void apot_quant_kernel(
        const float* __restrict__ x,
        const float* __restrict__ alpha_p,
        float* __restrict__ out,
        int n4, int n4_cut) {
    const float alpha_f = alpha_p[0];
    const float ape     = alpha_f + 1e-8f;   // 6.0f (1e-8 < half-ulp at 6)
    const float inv     = 1.0f / ape;        // IEEE f32 recip: 0x3E2AAAAB

    const vfloat4* __restrict__ x4   = reinterpret_cast<const vfloat4*>(x);
    vfloat4* __restrict__       out4 = reinterpret_cast<vfloat4*>(out);

    const int gs = gridDim.x * blockDim.x;
    int i = blockIdx.x * blockDim.x + threadIdx.x;

    // Unrolled x2: issue both loads before either compute.
    for (; i + gs < n4; i += 2 * gs) {
        int i1 = i + gs;
        vfloat4 v0 = (i  < n4_cut) ? x4[i]  : __builtin_nontemporal_load(&x4[i]);
        vfloat4 v1 = (i1 < n4_cut) ? x4[i1] : __builtin_nontemporal_load(&x4[i1]);
        vfloat4 r0 = apot_vec4(v0, inv, alpha_f);
        vfloat4 r1 = apot_vec4(v1, inv, alpha_f);
        __builtin_nontemporal_store(r0, &out4[i]);
        __builtin_nontemporal_store(r1, &out4[i1]);
    }
    if (i < n4) {
        vfloat4 v = (i < n4_cut) ? x4[i] : __builtin_nontemporal_load(&x4[i]);
        __builtin_nontemporal_store(apot_vec4(v, inv, alpha_f), &out4[i]);
    }
}

extern "C" void kernel_launch(void* const* d_in, const int* in_sizes, int n_in,
                              void* d_out, int out_size, void* d_ws, size_t ws_size,
                              hipStream_t stream) {
    const float* x     = (const float*)d_in[0];
    const float* alpha = (const float*)d_in[1];
    float*       out   = (float*)d_out;

    int n  = in_sizes[0];          // 8192*8192, divisible by 4
    int n4 = n >> 2;

    // 75% of the input via cacheable loads (192 MiB < 256 MiB L3), rest nt.
    int n4_cut = (int)(((long long)n4 * 3) / 4);

    int block = 256;
    int grid  = (n4 + block - 1) / block;
    if (grid > 2048) grid = 2048;  // 8 blocks/CU x 4 waves = 32 waves/CU

    apot_quant_kernel<<<grid, block, 0, stream>>>(x, alpha, out, n4, n4_cut);
}

// Round 7
// 89.696 us; speedup vs baseline: 1.0217x; 1.0217x over previous
//
#include <hip/hip_runtime.h>

// APoT quantization (BITS=5, K=2 -> N=2 banks, 4 levels/bank), elementwise.
// bank0 = {0, 1, 0.25, 0.0625}, bank1 = {0, 0.5, 0.125, 0.03125}, LMAX = 1.5
//
// Numeric contract (VERIFIED round 4, absmax = 0.0): all-f32 with
// reciprocal-multiply normalization xn = x * (1.0f/(alpha + 1e-8f))
// (XLA div->recip*mul rewrite; 1/6.0f = 0x3E2AAAAB), argmin first-index-wins,
// residual clip, acc/1.5f, *alpha_f32.  ARITHMETIC IS FROZEN.
//
// Memory path (final, = round-5 config, 89.5 us):
//  - cacheable vector loads (L3 serves ~50% of the input across replays;
//    partitioned nt-load scheme was tried in round 6: FETCH unchanged,
//    dur regressed -> nt is not honored as no-allocate for loads)
//  - nontemporal stores (round-4->5: 109.6 -> 89.5 us; writes bypass the
//    cache hierarchy and stop evicting the input)
//  - grid-stride, 2048 blocks x 256 threads = 32 waves/CU
// 89.5 us = 6.0 TB/s aggregate for 268 MB r + 268 MB w, within 5% of the
// 6.29 TB/s float4-copy ceiling measured on this chip.

typedef float vfloat4 __attribute__((ext_vector_type(4)));

__device__ __forceinline__ float apot_one(float x, float inv, float alpha_f) {
    float xn = fminf(fmaxf(x * inv, -1.0f), 1.0f);
    float s  = (xn > 0.0f) ? 1.0f : ((xn < 0.0f) ? -1.0f : 0.0f);
    float a  = fabsf(xn);

    // Bank 0: levels {0, 1, 0.25, 0.0625}; argmin first-index-wins (strict <)
    float best = a;          // |a - 0|
    float c0   = 0.0f;
    float d;
    d = fabsf(a - 1.0f);      if (d < best) { best = d; c0 = 1.0f; }
    d = fabsf(a - 0.25f);     if (d < best) { best = d; c0 = 0.25f; }
    d = fabsf(a - 0.0625f);   if (d < best) { best = d; c0 = 0.0625f; }
    float res = fmaxf(a - c0, 0.0f);   // exact in f32

    // Bank 1: levels {0, 0.5, 0.125, 0.03125}
    best = res;               // |res - 0| (res >= 0)
    float c1 = 0.0f;
    d = fabsf(res - 0.5f);     if (d < best) { best = d; c1 = 0.5f; }
    d = fabsf(res - 0.125f);   if (d < best) { best = d; c1 = 0.125f; }
    d = fabsf(res - 0.03125f); if (d < best) { best = d; c1 = 0.03125f; }

    float acc = c0 + c1;                               // exact
    float ah  = fminf(fmaxf(acc / 1.5f, 0.0f), 1.0f);  // (LMAX+EPS) -> 1.5f
    return s * ah * alpha_f;
}

__global__ __launch_bounds__(256) void apot_quant_kernel(
        const float* __restrict__ x,
        const float* __restrict__ alpha_p,
        float* __restrict__ out,
        int n4) {
    const float alpha_f = alpha_p[0];
    const float ape     = alpha_f + 1e-8f;   // 6.0f (1e-8 < half-ulp at 6)
    const float inv     = 1.0f / ape;        // IEEE f32 recip: 0x3E2AAAAB

    const vfloat4* __restrict__ x4   = reinterpret_cast<const vfloat4*>(x);
    vfloat4* __restrict__       out4 = reinterpret_cast<vfloat4*>(out);

    int stride = gridDim.x * blockDim.x;
    for (int i = blockIdx.x * blockDim.x + threadIdx.x; i < n4; i += stride) {
        vfloat4 v = x4[i];                 // cacheable load: L3 serves ~50%
        vfloat4 r;
        r.x = apot_one(v.x, inv, alpha_f);
        r.y = apot_one(v.y, inv, alpha_f);
        r.z = apot_one(v.z, inv, alpha_f);
        r.w = apot_one(v.w, inv, alpha_f);
        __builtin_nontemporal_store(r, &out4[i]);   // nt: don't evict input
    }
}

extern "C" void kernel_launch(void* const* d_in, const int* in_sizes, int n_in,
                              void* d_out, int out_size, void* d_ws, size_t ws_size,
                              hipStream_t stream) {
    const float* x     = (const float*)d_in[0];
    const float* alpha = (const float*)d_in[1];
    float*       out   = (float*)d_out;

    int n  = in_sizes[0];          // 8192*8192, divisible by 4
    int n4 = n >> 2;

    int block = 256;
    int grid  = (n4 + block - 1) / block;
    if (grid > 2048) grid = 2048;  // 8 blocks/CU x 4 waves = 32 waves/CU

    apot_quant_kernel<<<grid, block, 0, stream>>>(x, alpha, out, n4);
}